// Round 7
// baseline (332.625 us; speedup 1.0000x reference)
//
#include <hip/hip_runtime.h>
#include <hip/hip_bf16.h>

#define SEQ     2048
#define BATCH   2
#define HEADS   16
#define HD      128
#define SEGL    1024
#define QSCALE  0.08838834764831845f   // 1/sqrt(128)

typedef __attribute__((ext_vector_type(8))) short bf16x8;
typedef __attribute__((ext_vector_type(4))) float f32x4;
typedef unsigned int u32;

__device__ __forceinline__ short f2bf(float f) {
    __hip_bfloat16 h = __float2bfloat16(f);
    return *reinterpret_cast<short*>(&h);
}

__device__ __forceinline__ bf16x8 cvt8(f32x4 x, f32x4 y) {
    bf16x8 t;
    t[0]=f2bf(x[0]); t[1]=f2bf(x[1]); t[2]=f2bf(x[2]); t[3]=f2bf(x[3]);
    t[4]=f2bf(y[0]); t[5]=f2bf(y[1]); t[6]=f2bf(y[2]); t[7]=f2bf(y[3]);
    return t;
}

// async 16B/lane global->LDS copy; lds base must be wave-uniform
__device__ __forceinline__ void async16(void* lds, const void* g) {
    __builtin_amdgcn_global_load_lds(
        (const __attribute__((address_space(1))) u32*)g,
        (__attribute__((address_space(3))) u32*)lds, 16, 0, 0);
}

// ---------------------------------------------------------------------------
// prep:
//  z==0: K[s][b][h][d] fp32 -> KbfSw: per (bh, 64-row tile) 16KB region,
//        row-major [64 rows][16 chunks of 16B], chunk XOR-swizzled by (row&7)
//        (linear global_load_lds dest + swizzle pre-baked in source; attn
//        ds_reads with the same XOR).
//  z==1: V[s][b][h][d] fp32 -> Vfr in MFMA-fragment order:
//        idx = (oct*128 + d)*8 + e, oct = k-octet 0..7; a wave's fragment
//        read = base + lane*16B (coalesced 1KB).
// ---------------------------------------------------------------------------
__launch_bounds__(256)
__global__ void prep_kernel(const float* __restrict__ K, const float* __restrict__ V,
                            short* __restrict__ KbfSw, short* __restrict__ Vfr)
{
    const int t  = threadIdx.x;
    const int sT = blockIdx.x;        // 64-row s tile (0..31)
    const int bh = blockIdx.y;        // b*HEADS+h (0..31)
    const int b  = bh >> 4, h = bh & 15;
    const size_t inBase  = (size_t)sT * 64 * 4096 + (size_t)b * HEADS * HD + (size_t)h * HD;
    const size_t region  = ((size_t)bh * 32 + sT) * 8192;    // shorts (16KB)

    if (blockIdx.z == 0) {
        #pragma unroll
        for (int i = 0; i < 4; ++i) {
            const int idx = i * 256 + t;
            const int s_loc = idx >> 4, dg = idx & 15;
            const float* p = K + inBase + (size_t)s_loc * 4096 + dg * 8;
            f32x4 x = *(const f32x4*)p;
            f32x4 y = *(const f32x4*)(p + 4);
            *(bf16x8*)(KbfSw + region + s_loc * 128 + ((dg ^ (s_loc & 7)) * 8)) = cvt8(x, y);
        }
    } else {
        __shared__ __align__(16) short lds[64][136];
        #pragma unroll
        for (int i = 0; i < 4; ++i) {
            const int idx = i * 256 + t;
            const int s_loc = idx >> 4, dg = idx & 15;
            const float* p = V + inBase + (size_t)s_loc * 4096 + dg * 8;
            f32x4 x = *(const f32x4*)p;
            f32x4 y = *(const f32x4*)(p + 4);
            *(bf16x8*)(&lds[s_loc][dg * 8]) = cvt8(x, y);
        }
        __syncthreads();
        const int dp = t & 63;        // column pair: d = 2dp, 2dp+1
        const int g  = t >> 6;        // k-row group: rows g*16..g*16+15 (octets 2g,2g+1)
        bf16x8 a0, a1, b0_, b1_;
        #pragma unroll
        for (int j = 0; j < 8; ++j) {
            u32 v = *(const u32*)&lds[g * 16 + j][dp * 2];
            a0[j] = (short)(v & 0xffff);
            a1[j] = (short)(v >> 16);
        }
        #pragma unroll
        for (int j = 0; j < 8; ++j) {
            u32 v = *(const u32*)&lds[g * 16 + 8 + j][dp * 2];
            b0_[j] = (short)(v & 0xffff);
            b1_[j] = (short)(v >> 16);
        }
        short* rg = Vfr + region;
        *(bf16x8*)(rg + ((2 * g)     * 128 + 2 * dp)     * 8) = a0;
        *(bf16x8*)(rg + ((2 * g + 1) * 128 + 2 * dp)     * 8) = b0_;
        *(bf16x8*)(rg + ((2 * g)     * 128 + 2 * dp + 1) * 8) = a1;
        *(bf16x8*)(rg + ((2 * g + 1) * 128 + 2 * dp + 1) * 8) = b1_;
    }
}

// ---------------------------------------------------------------------------
// attention: block = 4 waves = 64 q rows of one (b,seg,h); KV tiles of 64.
// K: LDS-staged (dbuf, global_load_lds, swizzled).  V: register-direct from
// fragment-ordered Vfr (overlaps softmax).  Bias: prefetched 1 iter ahead.
// Row-sum reduction deferred to epilogue (per-lane partials in the loop).
// LDS 41KB -> 3 blocks/CU.
// ---------------------------------------------------------------------------
__launch_bounds__(256, 3)
__global__ void attn_fwd(const float* __restrict__ Q,
                         const short* __restrict__ KbfSw,
                         const short* __restrict__ Vfr,
                         const float* __restrict__ Bias,
                         float* __restrict__ Out)
{
    __shared__ __align__(16) short kbuf[2][8192];
    __shared__ __align__(16) short plds_all[4][16][72];

    const int tid = threadIdx.x;
    const int w   = tid >> 6;
    const int l   = tid & 63;
    const int lo4 = l & 15;
    const int hi4 = l >> 4;
    const int sw  = lo4 & 7;                  // ds_read swizzle key

    const int bsh = blockIdx.x & 63;
    const int st  = 15 - (blockIdx.x >> 6);   // longest q-supertiles first
    const int h   = bsh & 15;
    const int seg = (bsh >> 4) & 1;
    const int b   = bsh >> 5;
    const int bh  = b * HEADS + h;

    const int segBase = seg * SEGL;
    const int i0  = st * 64 + w * 16;         // wave's q-row base (segment-local)
    const int njt = st + 1;

    short (*plds)[72] = plds_all[w];

    // ---- Q fragments (fp32, once) ----
    bf16x8 qf[4];
    {
        const float* qp = Q + (size_t)(segBase + i0 + lo4) * 4096
                            + (size_t)b * HEADS * HD + (size_t)h * HD + 8 * hi4;
        #pragma unroll
        for (int c = 0; c < 4; ++c) {
            f32x4 x = *(const f32x4*)(qp + 32 * c);
            f32x4 y = *(const f32x4*)(qp + 32 * c + 4);
            qf[c] = cvt8(x, y);
        }
    }

    f32x4 o[8];
    #pragma unroll
    for (int d = 0; d < 8; ++d) o[d] = (f32x4){0.f, 0.f, 0.f, 0.f};
    float m_run[4] = {-INFINITY, -INFINITY, -INFINITY, -INFINITY};
    float l_run[4] = {0.f, 0.f, 0.f, 0.f};    // per-lane PARTIAL sums

    const short* kReg = KbfSw + ((size_t)bh * 32 + seg * 16) * 8192;
    const short* vSeg = Vfr  + ((size_t)bh * 32 + seg * 16) * 8192;
    const float* bbase = Bias + ((size_t)b * SEQ + segBase) * SEQ + segBase;

    const int ldsOff = w * 2048;              // wave-uniform LDS offset (shorts)
    const int srcOff = w * 2048 + l * 8;      // per-lane global offset (shorts)

    // ---- prologue: stage K tile 0; load bias tile 0 ----
    #pragma unroll
    for (int c = 0; c < 4; ++c)
        async16(&kbuf[0][ldsOff + c * 512], kReg + srcOff + c * 512);

    float bvA[4][4];
    #pragma unroll
    for (int r = 0; r < 4; ++r) {
        const float* bp = bbase + (size_t)(i0 + 4 * hi4 + r) * SEQ;
        #pragma unroll
        for (int ct = 0; ct < 4; ++ct) bvA[r][ct] = bp[ct * 16 + lo4];
    }
    __syncthreads();

    for (int jt = 0; jt < njt; ++jt) {
        const int cur = jt & 1;
        const int j0  = jt * 64;
        const short* vReg = vSeg + (size_t)jt * 8192;

        // ---- issue next K stage (flies under this tile's compute) ----
        if (jt + 1 < njt) {
            const short* kN = kReg + (size_t)(jt + 1) * 8192;
            #pragma unroll
            for (int c = 0; c < 4; ++c)
                async16(&kbuf[cur ^ 1][ldsOff + c * 512], kN + srcOff + c * 512);
        }

        // ---- V fragment loads, register-direct (cover = QK + softmax) ----
        const short* vpa = vReg + hi4 * 1024 + lo4 * 8;
        const short* vpb = vReg + (4 + hi4) * 1024 + lo4 * 8;
        bf16x8 vfa[8], vfb[8];
        #pragma unroll
        for (int d0 = 0; d0 < 8; ++d0) vfa[d0] = *(const bf16x8*)(vpa + d0 * 128);
        #pragma unroll
        for (int d0 = 0; d0 < 8; ++d0) vfb[d0] = *(const bf16x8*)(vpb + d0 * 128);

        // ---- bias prefetch for t+1 ----
        float bvB[4][4];
        if (jt + 1 < njt) {
            #pragma unroll
            for (int r = 0; r < 4; ++r) {
                const float* bp = bbase + (size_t)(i0 + 4 * hi4 + r) * SEQ + j0 + 64;
                #pragma unroll
                for (int ct = 0; ct < 4; ++ct) bvB[r][ct] = bp[ct * 16 + lo4];
            }
        }

        // ---- S = Q K^T from staged kbuf (swizzled ds_read_b128) ----
        f32x4 s[4];
        #pragma unroll
        for (int ct = 0; ct < 4; ++ct) s[ct] = (f32x4){0.f, 0.f, 0.f, 0.f};
        #pragma unroll
        for (int ct = 0; ct < 4; ++ct) {
            bf16x8 kf[4];
            const short* kr = kbuf[cur] + (ct * 16 + lo4) * 128;
            #pragma unroll
            for (int c = 0; c < 4; ++c)
                kf[c] = *(const bf16x8*)(kr + (((4 * c + hi4) ^ sw) * 8));
            #pragma unroll
            for (int c = 0; c < 4; ++c)
                s[ct] = __builtin_amdgcn_mfma_f32_16x16x32_bf16(qf[c], kf[c], s[ct], 0, 0, 0);
        }

        // ---- scale + bias (+ causal mask on diagonal tile) + online softmax ----
        const bool diag = (jt == njt - 1);
        #pragma unroll
        for (int r = 0; r < 4; ++r) {
            const int qr = i0 + 4 * hi4 + r;
            float v0 = s[0][r] * QSCALE + bvA[r][0];
            float v1 = s[1][r] * QSCALE + bvA[r][1];
            float v2 = s[2][r] * QSCALE + bvA[r][2];
            float v3 = s[3][r] * QSCALE + bvA[r][3];
            if (diag) {
                if (j0 + lo4 > qr)      v0 = -INFINITY;
                if (j0 + 16 + lo4 > qr) v1 = -INFINITY;
                if (j0 + 32 + lo4 > qr) v2 = -INFINITY;
                if (j0 + 48 + lo4 > qr) v3 = -INFINITY;
            }
            float mx = fmaxf(fmaxf(v0, v1), fmaxf(v2, v3));
            mx = fmaxf(mx, __shfl_xor(mx, 1));
            mx = fmaxf(mx, __shfl_xor(mx, 2));
            mx = fmaxf(mx, __shfl_xor(mx, 4));
            mx = fmaxf(mx, __shfl_xor(mx, 8));
            const float mnew = fmaxf(m_run[r], mx);
            const float p0 = __expf(v0 - mnew);
            const float p1 = __expf(v1 - mnew);
            const float p2 = __expf(v2 - mnew);
            const float p3 = __expf(v3 - mnew);
            const float sc = __expf(m_run[r] - mnew);
            m_run[r] = mnew;
            // per-lane partial row sum; cross-lane reduce deferred to epilogue
            l_run[r] = l_run[r] * sc + (p0 + p1 + p2 + p3);
            #pragma unroll
            for (int d = 0; d < 8; ++d) o[d][r] *= sc;

            short* prow = plds[4 * hi4 + r];
            prow[lo4]      = f2bf(p0);
            prow[16 + lo4] = f2bf(p1);
            prow[32 + lo4] = f2bf(p2);
            prow[48 + lo4] = f2bf(p3);
        }

        // wave-private LDS round-trip (C-layout -> A-layout)
        asm volatile("s_waitcnt lgkmcnt(0)" ::: "memory");
        bf16x8 pf0 = *(const bf16x8*)(&plds[lo4][8 * hi4]);
        bf16x8 pf1 = *(const bf16x8*)(&plds[lo4][32 + 8 * hi4]);

        // ---- O += P V ----
        #pragma unroll
        for (int d0 = 0; d0 < 8; ++d0)
            o[d0] = __builtin_amdgcn_mfma_f32_16x16x32_bf16(pf0, vfa[d0], o[d0], 0, 0, 0);
        #pragma unroll
        for (int d0 = 0; d0 < 8; ++d0)
            o[d0] = __builtin_amdgcn_mfma_f32_16x16x32_bf16(pf1, vfb[d0], o[d0], 0, 0, 0);

        // ---- rotate bias prefetch ----
        if (jt + 1 < njt) {
            #pragma unroll
            for (int r = 0; r < 4; ++r)
                #pragma unroll
                for (int ct = 0; ct < 4; ++ct) bvA[r][ct] = bvB[r][ct];
        }

        __syncthreads();   // protects kbuf; drains stage + prefetch vmcnt
    }

    // ---- epilogue: cross-lane sum reduce (once), normalize, store ----
    #pragma unroll
    for (int r = 0; r < 4; ++r) {
        float rs = l_run[r];
        rs += __shfl_xor(rs, 1);
        rs += __shfl_xor(rs, 2);
        rs += __shfl_xor(rs, 4);
        rs += __shfl_xor(rs, 8);
        const float inv = 1.0f / rs;
        const int srow = segBase + i0 + 4 * hi4 + r;
        float* op = Out + ((size_t)bh * SEQ + (size_t)srow) * HD + lo4;
        #pragma unroll
        for (int d = 0; d < 8; ++d)
            op[d * 16] = o[d][r] * inv;
    }
}

extern "C" void kernel_launch(void* const* d_in, const int* in_sizes, int n_in,
                              void* d_out, int out_size, void* d_ws, size_t ws_size,
                              hipStream_t stream) {
    const float* Q    = (const float*)d_in[0];
    const float* K    = (const float*)d_in[1];
    const float* V    = (const float*)d_in[2];
    const float* Bias = (const float*)d_in[3];
    float* Out = (float*)d_out;

    short* KbfSw = (short*)d_ws;                         // 16 MiB
    short* Vfr   = (short*)d_ws + (size_t)8388608;       // 16 MiB

    hipLaunchKernelGGL(prep_kernel, dim3(32, 32, 2), dim3(256), 0, stream, K, V, KbfSw, Vfr);
    hipLaunchKernelGGL(attn_fwd, dim3(1024), dim3(256), 0, stream, Q, KbfSw, Vfr, Bias, Out);
}

// Round 8
// 208.749 us; speedup vs baseline: 1.5934x; 1.5934x over previous
//
#include <hip/hip_runtime.h>
#include <hip/hip_bf16.h>

#define SEQ     2048
#define BATCH   2
#define HEADS   16
#define HD      128
#define SEGL    1024
#define QSCALE  0.08838834764831845f   // 1/sqrt(128)

typedef __attribute__((ext_vector_type(8))) short bf16x8;
typedef __attribute__((ext_vector_type(4))) float f32x4;
typedef unsigned int u32;

__device__ __forceinline__ short f2bf(float f) {
    __hip_bfloat16 h = __float2bfloat16(f);
    return *reinterpret_cast<short*>(&h);
}

__device__ __forceinline__ bf16x8 cvt8(f32x4 x, f32x4 y) {
    bf16x8 t;
    t[0]=f2bf(x[0]); t[1]=f2bf(x[1]); t[2]=f2bf(x[2]); t[3]=f2bf(x[3]);
    t[4]=f2bf(y[0]); t[5]=f2bf(y[1]); t[6]=f2bf(y[2]); t[7]=f2bf(y[3]);
    return t;
}

// async 16B/lane global->LDS copy; lds base must be wave-uniform
__device__ __forceinline__ void async16(void* lds, const void* g) {
    __builtin_amdgcn_global_load_lds(
        (const __attribute__((address_space(1))) u32*)g,
        (__attribute__((address_space(3))) u32*)lds, 16, 0, 0);
}

// ---------------------------------------------------------------------------
// prep (identical to round-4 version, which measured correct):
//  z==0: K fp32 -> KbfSw: per (bh, 64-row tile) 16KB region, [64 rows][16
//        chunks of 16B], chunk XOR-swizzled by (row&7).
//  z==1: V fp32 -> VtSw: per (bh, tile) region [128 d][8 chunks of 16B],
//        chunk XOR-swizzled by (d&7).
// ---------------------------------------------------------------------------
__launch_bounds__(256)
__global__ void prep_kernel(const float* __restrict__ K, const float* __restrict__ V,
                            short* __restrict__ KbfSw, short* __restrict__ VtSw)
{
    const int t  = threadIdx.x;
    const int sT = blockIdx.x;
    const int bh = blockIdx.y;
    const int b  = bh >> 4, h = bh & 15;
    const size_t inBase  = (size_t)sT * 64 * 4096 + (size_t)b * HEADS * HD + (size_t)h * HD;
    const size_t region  = ((size_t)bh * 32 + sT) * 8192;

    if (blockIdx.z == 0) {
        #pragma unroll
        for (int i = 0; i < 4; ++i) {
            const int idx = i * 256 + t;
            const int s_loc = idx >> 4, dg = idx & 15;
            const float* p = K + inBase + (size_t)s_loc * 4096 + dg * 8;
            f32x4 x = *(const f32x4*)p;
            f32x4 y = *(const f32x4*)(p + 4);
            *(bf16x8*)(KbfSw + region + s_loc * 128 + ((dg ^ (s_loc & 7)) * 8)) = cvt8(x, y);
        }
    } else {
        __shared__ __align__(16) short lds[64][136];
        #pragma unroll
        for (int i = 0; i < 4; ++i) {
            const int idx = i * 256 + t;
            const int s_loc = idx >> 4, dg = idx & 15;
            const float* p = V + inBase + (size_t)s_loc * 4096 + dg * 8;
            f32x4 x = *(const f32x4*)p;
            f32x4 y = *(const f32x4*)(p + 4);
            *(bf16x8*)(&lds[s_loc][dg * 8]) = cvt8(x, y);
        }
        __syncthreads();
        const int dp = t & 63;
        const int g  = t >> 6;
        bf16x8 a0, a1, b0_, b1_;
        #pragma unroll
        for (int j = 0; j < 8; ++j) {
            u32 v = *(const u32*)&lds[g * 16 + j][dp * 2];
            a0[j] = (short)(v & 0xffff);
            a1[j] = (short)(v >> 16);
        }
        #pragma unroll
        for (int j = 0; j < 8; ++j) {
            u32 v = *(const u32*)&lds[g * 16 + 8 + j][dp * 2];
            b0_[j] = (short)(v & 0xffff);
            b1_[j] = (short)(v >> 16);
        }
        const int d0c = dp * 2, d1c = dp * 2 + 1;
        short* base0 = VtSw + region + d0c * 64;
        short* base1 = VtSw + region + d1c * 64;
        *(bf16x8*)(base0 + (((g * 2)     ^ (d0c & 7)) * 8)) = a0;
        *(bf16x8*)(base0 + (((g * 2 + 1) ^ (d0c & 7)) * 8)) = b0_;
        *(bf16x8*)(base1 + (((g * 2)     ^ (d1c & 7)) * 8)) = a1;
        *(bf16x8*)(base1 + (((g * 2 + 1) ^ (d1c & 7)) * 8)) = b1_;
    }
}

// ---------------------------------------------------------------------------
// attention (round-4 skeleton + counted-vmcnt pipeline):
// block = 4 waves = 64 q rows; K+V 64-row tiles double-buffered in LDS via
// global_load_lds.  Per iter: barrier1 -> issue stage(jt+1) -> vmcnt(8)
// (stage(jt+1) stays in flight) -> barrier2 -> compute.  Never vmcnt(0) in
// the main loop.  Bias double-buffered in registers, one iter ahead.
// Row-sum reduction deferred to epilogue.
// ---------------------------------------------------------------------------
__launch_bounds__(256, 2)
__global__ void attn_fwd(const float* __restrict__ Q,
                         const short* __restrict__ KbfSw,
                         const short* __restrict__ VtSw,
                         const float* __restrict__ Bias,
                         float* __restrict__ Out)
{
    __shared__ __align__(16) short kbuf[2][8192];
    __shared__ __align__(16) short vbuf[2][8192];
    __shared__ __align__(16) short plds_all[4][16][72];

    const int tid = threadIdx.x;
    const int w   = tid >> 6;
    const int l   = tid & 63;
    const int lo4 = l & 15;
    const int hi4 = l >> 4;
    const int sw  = lo4 & 7;                  // ds_read swizzle key

    const int bsh = blockIdx.x & 63;
    const int st  = 15 - (blockIdx.x >> 6);   // longest q-supertiles first
    const int h   = bsh & 15;
    const int seg = (bsh >> 4) & 1;
    const int b   = bsh >> 5;
    const int bh  = b * HEADS + h;

    const int segBase = seg * SEGL;
    const int i0  = st * 64 + w * 16;
    const int njt = st + 1;

    short (*plds)[72] = plds_all[w];

    // ---- Q fragments (fp32, once) ----
    bf16x8 qf[4];
    {
        const float* qp = Q + (size_t)(segBase + i0 + lo4) * 4096
                            + (size_t)b * HEADS * HD + (size_t)h * HD + 8 * hi4;
        #pragma unroll
        for (int c = 0; c < 4; ++c) {
            f32x4 x = *(const f32x4*)(qp + 32 * c);
            f32x4 y = *(const f32x4*)(qp + 32 * c + 4);
            qf[c] = cvt8(x, y);
        }
    }

    f32x4 o[8];
    #pragma unroll
    for (int d = 0; d < 8; ++d) o[d] = (f32x4){0.f, 0.f, 0.f, 0.f};
    float m_run[4] = {-INFINITY, -INFINITY, -INFINITY, -INFINITY};
    float l_run[4] = {0.f, 0.f, 0.f, 0.f};    // per-lane PARTIAL sums

    const short* kReg = KbfSw + ((size_t)bh * 32 + seg * 16) * 8192;
    const short* vReg = VtSw  + ((size_t)bh * 32 + seg * 16) * 8192;
    const float* bbase = Bias + ((size_t)b * SEQ + segBase) * SEQ + segBase;

    const int ldsOff = w * 2048;              // wave-uniform LDS offset (shorts)
    const int srcOff = w * 2048 + l * 8;      // per-lane global offset (shorts)

    // ---- prologue: stage tile 0, bias tile 0; single full drain ----
    #pragma unroll
    for (int c = 0; c < 4; ++c) {
        async16(&kbuf[0][ldsOff + c * 512], kReg + srcOff + c * 512);
        async16(&vbuf[0][ldsOff + c * 512], vReg + srcOff + c * 512);
    }
    float bvA[4][4];
    #pragma unroll
    for (int r = 0; r < 4; ++r) {
        const float* bp = bbase + (size_t)(i0 + 4 * hi4 + r) * SEQ;
        #pragma unroll
        for (int ct = 0; ct < 4; ++ct) bvA[r][ct] = bp[ct * 16 + lo4];
    }
    __syncthreads();

    for (int jt = 0; jt < njt; ++jt) {
        const int cur = jt & 1;
        const int j0  = jt * 64;
        const bool more = (jt + 1 < njt);   // uniform across the block

        if (more) {
            // all waves done reading buf[cur^1] (its ds_reads were consumed
            // by MFMAs last iteration)
            asm volatile("s_barrier" ::: "memory");
            const short* kN = kReg + (size_t)(jt + 1) * 8192;
            const short* vN = vReg + (size_t)(jt + 1) * 8192;
            #pragma unroll
            for (int c = 0; c < 4; ++c) {
                async16(&kbuf[cur ^ 1][ldsOff + c * 512], kN + srcOff + c * 512);
                async16(&vbuf[cur ^ 1][ldsOff + c * 512], vN + srcOff + c * 512);
            }
            // wait my stage(jt) + bias(jt); leave stage(jt+1)'s 8 in flight
            asm volatile("s_waitcnt vmcnt(8)" ::: "memory");
        } else {
            asm volatile("s_waitcnt vmcnt(0)" ::: "memory");
        }
        // all waves' stage(jt) DMA landed
        asm volatile("s_barrier" ::: "memory");

        // ---- bias prefetch for jt+1 (newest vmcnt entries; drained by
        //      next iteration's vmcnt(8)) ----
        float bvB[4][4];
        if (more) {
            #pragma unroll
            for (int r = 0; r < 4; ++r) {
                const float* bp = bbase + (size_t)(i0 + 4 * hi4 + r) * SEQ + j0 + 64;
                #pragma unroll
                for (int ct = 0; ct < 4; ++ct) bvB[r][ct] = bp[ct * 16 + lo4];
            }
        }

        // ---- S = Q K^T from kbuf (swizzled ds_read_b128) ----
        f32x4 s[4];
        #pragma unroll
        for (int ct = 0; ct < 4; ++ct) s[ct] = (f32x4){0.f, 0.f, 0.f, 0.f};
        #pragma unroll
        for (int ct = 0; ct < 4; ++ct) {
            bf16x8 kf[4];
            const short* kr = kbuf[cur] + (ct * 16 + lo4) * 128;
            #pragma unroll
            for (int c = 0; c < 4; ++c)
                kf[c] = *(const bf16x8*)(kr + (((4 * c + hi4) ^ sw) * 8));
            #pragma unroll
            for (int c = 0; c < 4; ++c)
                s[ct] = __builtin_amdgcn_mfma_f32_16x16x32_bf16(qf[c], kf[c], s[ct], 0, 0, 0);
        }

        // ---- V fragments from vbuf (overlap softmax) ----
        bf16x8 vfa[8], vfb[8];
        #pragma unroll
        for (int d0 = 0; d0 < 8; ++d0) {
            const short* vr = vbuf[cur] + (d0 * 16 + lo4) * 64;
            vfa[d0] = *(const bf16x8*)(vr + ((hi4 ^ sw) * 8));
            vfb[d0] = *(const bf16x8*)(vr + (((4 + hi4) ^ sw) * 8));
        }

        // ---- scale + bias (+ causal mask on diagonal tile) + online softmax ----
        const bool diag = (jt == njt - 1);
        #pragma unroll
        for (int r = 0; r < 4; ++r) {
            const int qr = i0 + 4 * hi4 + r;
            float v0 = s[0][r] * QSCALE + bvA[r][0];
            float v1 = s[1][r] * QSCALE + bvA[r][1];
            float v2 = s[2][r] * QSCALE + bvA[r][2];
            float v3 = s[3][r] * QSCALE + bvA[r][3];
            if (diag) {
                if (j0 + lo4 > qr)      v0 = -INFINITY;
                if (j0 + 16 + lo4 > qr) v1 = -INFINITY;
                if (j0 + 32 + lo4 > qr) v2 = -INFINITY;
                if (j0 + 48 + lo4 > qr) v3 = -INFINITY;
            }
            float mx = fmaxf(fmaxf(v0, v1), fmaxf(v2, v3));
            mx = fmaxf(mx, __shfl_xor(mx, 1));
            mx = fmaxf(mx, __shfl_xor(mx, 2));
            mx = fmaxf(mx, __shfl_xor(mx, 4));
            mx = fmaxf(mx, __shfl_xor(mx, 8));
            const float mnew = fmaxf(m_run[r], mx);
            const float p0 = __expf(v0 - mnew);
            const float p1 = __expf(v1 - mnew);
            const float p2 = __expf(v2 - mnew);
            const float p3 = __expf(v3 - mnew);
            const float sc = __expf(m_run[r] - mnew);
            m_run[r] = mnew;
            l_run[r] = l_run[r] * sc + (p0 + p1 + p2 + p3);
            #pragma unroll
            for (int d = 0; d < 8; ++d) o[d][r] *= sc;

            short* prow = plds[4 * hi4 + r];
            prow[lo4]      = f2bf(p0);
            prow[16 + lo4] = f2bf(p1);
            prow[32 + lo4] = f2bf(p2);
            prow[48 + lo4] = f2bf(p3);
        }

        // wave-private LDS round-trip (C-layout -> A-layout)
        asm volatile("s_waitcnt lgkmcnt(0)" ::: "memory");
        bf16x8 pf0 = *(const bf16x8*)(&plds[lo4][8 * hi4]);
        bf16x8 pf1 = *(const bf16x8*)(&plds[lo4][32 + 8 * hi4]);

        // ---- O += P V ----
        #pragma unroll
        for (int d0 = 0; d0 < 8; ++d0) {
            o[d0] = __builtin_amdgcn_mfma_f32_16x16x32_bf16(pf0, vfa[d0], o[d0], 0, 0, 0);
            o[d0] = __builtin_amdgcn_mfma_f32_16x16x32_bf16(pf1, vfb[d0], o[d0], 0, 0, 0);
        }

        // ---- rotate bias prefetch ----
        if (more) {
            #pragma unroll
            for (int r = 0; r < 4; ++r)
                #pragma unroll
                for (int ct = 0; ct < 4; ++ct) bvA[r][ct] = bvB[r][ct];
        }
    }

    // ---- epilogue: cross-lane sum reduce (once), normalize, store ----
    #pragma unroll
    for (int r = 0; r < 4; ++r) {
        float rs = l_run[r];
        rs += __shfl_xor(rs, 1);
        rs += __shfl_xor(rs, 2);
        rs += __shfl_xor(rs, 4);
        rs += __shfl_xor(rs, 8);
        const float inv = 1.0f / rs;
        const int srow = segBase + i0 + 4 * hi4 + r;
        float* op = Out + ((size_t)bh * SEQ + (size_t)srow) * HD + lo4;
        #pragma unroll
        for (int d = 0; d < 8; ++d)
            op[d * 16] = o[d][r] * inv;
    }
}

extern "C" void kernel_launch(void* const* d_in, const int* in_sizes, int n_in,
                              void* d_out, int out_size, void* d_ws, size_t ws_size,
                              hipStream_t stream) {
    const float* Q    = (const float*)d_in[0];
    const float* K    = (const float*)d_in[1];
    const float* V    = (const float*)d_in[2];
    const float* Bias = (const float*)d_in[3];
    float* Out = (float*)d_out;

    short* KbfSw = (short*)d_ws;                         // 16 MiB
    short* VtSw  = (short*)d_ws + (size_t)8388608;       // 16 MiB

    hipLaunchKernelGGL(prep_kernel, dim3(32, 32, 2), dim3(256), 0, stream, K, V, KbfSw, VtSw);
    hipLaunchKernelGGL(attn_fwd, dim3(1024), dim3(256), 0, stream, Q, KbfSw, VtSw, Bias, Out);
}